// Round 17
// baseline (134.713 us; speedup 1.0000x reference)
//
#include <hip/hip_runtime.h>
#include <cstdint>

#define D_MODEL 1536
#define BATCH   8192
#define EPS     1e-8f

#define BM 128
#define BN 96        // multiple of 3: quaternion blocks never straddle a tile
#define BK 32
#define NT (D_MODEL / BK)    // 48 K-tiles
#define NTN (D_MODEL / BN)   // 16
#define NTM (BATCH / BM)     // 64
#define BUF 20480            // bytes per LDS buffer (A 8192 + B1 6144 + B2 6144)

typedef __attribute__((ext_vector_type(8))) short bf16x8;
typedef __attribute__((ext_vector_type(8))) unsigned short ushort8;
typedef __attribute__((ext_vector_type(4))) float f32x4;

__device__ __forceinline__ unsigned short f2bf(float f) {
  unsigned u = __builtin_bit_cast(unsigned, f);
  u += 0x7fffu + ((u >> 16) & 1u);            // round-to-nearest-even
  return (unsigned short)(u >> 16);
}

__device__ __forceinline__ ushort8 pack8u(float4 a, float4 b) {
  ushort8 o;
  o[0] = f2bf(a.x); o[1] = f2bf(a.y); o[2] = f2bf(a.z); o[3] = f2bf(a.w);
  o[4] = f2bf(b.x); o[5] = f2bf(b.y); o[6] = f2bf(b.z); o[7] = f2bf(b.w);
  return o;
}

__device__ __forceinline__ void full_drain() {
  asm volatile("s_waitcnt vmcnt(0) lgkmcnt(0)" ::: "memory");
}
__device__ __forceinline__ void vm_drain() {
  asm volatile("s_waitcnt vmcnt(0)" ::: "memory");
}
__device__ __forceinline__ void lgkm_drain() {
  asm volatile("s_waitcnt lgkmcnt(0)" ::: "memory");
}

__device__ __forceinline__ void load_lds16(const void* g, void* l) {
  __builtin_amdgcn_global_load_lds(
      (const __attribute__((address_space(1))) unsigned int*)g,
      (__attribute__((address_space(3))) unsigned int*)l,
      16, 0, 0);
}

// ---------------- prep_all: x->bf16 + decay (blocks 0..2047),
//                  weights->bf16 (blocks 2048..3071) ----------------------
__global__ void prep_all(const float* __restrict__ x,
                         const float* __restrict__ wdec,
                         const float* __restrict__ bdec,
                         const float* __restrict__ wbiv,
                         const float* __restrict__ win,
                         unsigned short* __restrict__ xb,
                         unsigned short* __restrict__ wb,
                         float* __restrict__ decay) {
  const int b = blockIdx.x;
  if (b < 2048) {
    int row  = (int)((b * 256 + threadIdx.x) >> 6);
    int lane = threadIdx.x & 63;
    const float4* xr = (const float4*)(x + (long)row * D_MODEL);
    const float4* wr = (const float4*)wdec;
    unsigned short* xo = xb + (long)row * D_MODEL;
    float acc = 0.f;
#pragma unroll
    for (int i = 0; i < 6; ++i) {                // 6*64*4 = 1536
      float4 a = xr[lane + 64 * i];
      float4 w = wr[lane + 64 * i];
      acc += a.x * w.x + a.y * w.y + a.z * w.z + a.w * w.w;
      ushort4 o;
      o.x = f2bf(a.x); o.y = f2bf(a.y); o.z = f2bf(a.z); o.w = f2bf(a.w);
      *(ushort4*)(xo + (lane + 64 * i) * 4) = o;
    }
    for (int off = 32; off; off >>= 1) acc += __shfl_xor(acc, off);
    if (lane == 0) decay[row] = 1.f / (1.f + expf(-(acc + bdec[0])));
  } else {
    const long NW4 = (long)D_MODEL * D_MODEL / 4;
    for (long i = (long)(b - 2048) * 256 + threadIdx.x; i < 2 * NW4;
         i += (long)1024 * 256) {
      const float4* src = (i < NW4) ? (const float4*)wbiv : (const float4*)win;
      long j = (i < NW4) ? i : (i - NW4);
      float4 v = src[j];
      ushort4 o;
      o.x = f2bf(v.x); o.y = f2bf(v.y); o.z = f2bf(v.z); o.w = f2bf(v.w);
      *(ushort4*)(wb + 4 * i) = o;
    }
  }
}

// ---------------- main: dual-GEMM + quaternion epilogue -------------------
// r16 structure with BK=32: identical fence-region size (8 ds_read + 12 MFMA),
// half-size double buffer -> 3 blocks/CU (LDS 49664). Swizzle adapted to
// 4-slot rows: cs = c ^ ((row>>1)&3) on BOTH source and read sides.
__global__ __launch_bounds__(512, 2)
void fused_main(const unsigned short* __restrict__ xb,
                const unsigned short* __restrict__ wb,
                const float* __restrict__ hprev,
                const float* __restrict__ decay,
                const float* __restrict__ bbiv,
                const float* __restrict__ bin,
                float* __restrict__ out) {
  __shared__ __align__(16) char smem[49664];     // max(2*BUF, 128*97*4)
  float* sBv = (float*)smem;                     // [128][97] epilogue overlay

  const int bid = blockIdx.x;
  const int tm = bid / NTN, tn = bid % NTN;
  const int m0 = tm * BM, n0 = tn * BN;
  const int tid  = threadIdx.x;
  const int lane = tid & 63, wid = tid >> 6;
  const int wr = wid >> 1, wc = wid & 1;   // 4x2 wave grid: 32x48 per wave
  const int lr = lane & 15;                // fragment row/col
  const int lk = lane >> 4;                // k-octet group

  // ---- hoisted STAGE addressing (global ptrs advance BK per tile) ----
  const unsigned short *gA, *gB1, *gB2;
  int dA, dB1, dB2;
  {
    int f, row, c, cs;
    f = tid;  row = f >> 2; c = f & 3; cs = c ^ ((row >> 1) & 3);
    gA = xb + (long)(m0 + row) * D_MODEL + cs * 8;          // all 512 threads
    dA = (wid * 64) << 4;
    // B chunks: 384 per matrix, waves 0..5 (tid<384)
    row = f >> 2; c = f & 3; cs = c ^ ((row >> 1) & 3);
    gB1 = wb + (long)(n0 + row) * D_MODEL + cs * 8;
    gB2 = gB1 + (long)D_MODEL * D_MODEL;
    dB1 = 8192 + ((wid * 64) << 4);
    dB2 = dB1 + 6144;
  }

  auto STAGE = [&](int bb) {
    load_lds16(gA, smem + bb + dA);
    if (tid < 384) {
      load_lds16(gB1, smem + bb + dB1);
      load_lds16(gB2, smem + bb + dB2);
    }
    gA += BK; gB1 += BK; gB2 += BK;
  };

  // acc*[mi][ni][r] == C[wr*32+mi*16+lk*4+r][n0+wc*48+ni*16+lr]
  f32x4 accB[2][3], accI[2][3];
#pragma unroll
  for (int a = 0; a < 2; ++a)
#pragma unroll
    for (int b = 0; b < 3; ++b) { accB[a][b] = (f32x4)0.f; accI[a][b] = (f32x4)0.f; }

  // prologue: fill buffer 0
  STAGE(0);
  vm_drain();
  __syncthreads();

  for (int t = 0; t < NT; ++t) {
    const int cur = (t & 1) * BUF;
    if (t + 1 < NT) STAGE(((t + 1) & 1) * BUF);   // prefetch next tile

    const unsigned short* cA  = (const unsigned short*)(smem + cur);
    const unsigned short* cB1 = (const unsigned short*)(smem + cur + 8192);
    const unsigned short* cB2 = (const unsigned short*)(smem + cur + 14336);

    {
      bf16x8 a[2], b1[3], b2[3];
#pragma unroll
      for (int mi = 0; mi < 2; ++mi) {
        int R = wr * 32 + mi * 16 + lr;
        a[mi] = *(const bf16x8*)(cA + R * 32 + (lk ^ ((R >> 1) & 3)) * 8);
      }
#pragma unroll
      for (int ni = 0; ni < 3; ++ni) {
        int R = wc * 48 + ni * 16 + lr;
        b1[ni] = *(const bf16x8*)(cB1 + R * 32 + (lk ^ ((R >> 1) & 3)) * 8);
        b2[ni] = *(const bf16x8*)(cB2 + R * 32 + (lk ^ ((R >> 1) & 3)) * 8);
      }
      lgkm_drain();                          // operands in registers
      __builtin_amdgcn_sched_barrier(0);     // no reorder into MFMA chain
#pragma unroll
      for (int mi = 0; mi < 2; ++mi)
#pragma unroll
        for (int ni = 0; ni < 3; ++ni)
          accB[mi][ni] = __builtin_amdgcn_mfma_f32_16x16x32_bf16(
              a[mi], b1[ni], accB[mi][ni], 0, 0, 0);
      __builtin_amdgcn_sched_barrier(0);     // no chain interleave
#pragma unroll
      for (int mi = 0; mi < 2; ++mi)
#pragma unroll
        for (int ni = 0; ni < 3; ++ni)
          accI[mi][ni] = __builtin_amdgcn_mfma_f32_16x16x32_bf16(
              a[mi], b2[ni], accI[mi][ni], 0, 0, 0);
      __builtin_amdgcn_sched_barrier(0);
    }

    vm_drain();        // prefetched tile landed; LDS reads already drained
    __syncthreads();   // safe to overwrite buffer (t&1) next iteration
  }

  // ---- epilogue (r16 logic) ----
#pragma unroll
  for (int mi = 0; mi < 2; ++mi)
#pragma unroll
    for (int ni = 0; ni < 3; ++ni) {
      int col = wc * 48 + ni * 16 + lr;
      float bb = bbiv[n0 + col];
#pragma unroll
      for (int r = 0; r < 4; ++r) {
        int row = wr * 32 + mi * 16 + lk * 4 + r;
        sBv[row * 97 + col] = accB[mi][ni][r] + bb;
      }
    }
  full_drain();
  __syncthreads();

#pragma unroll
  for (int mi = 0; mi < 2; ++mi)
#pragma unroll
    for (int ni = 0; ni < 3; ++ni) {
      int col  = wc * 48 + ni * 16 + lr;
      int gcol = n0 + col;
      int c    = (col % 3);        // n0 % 3 == 0
      int lc0  = col - c;
      float binv = bin[gcol];
#pragma unroll
      for (int r = 0; r < 4; ++r) {
        int row  = wr * 32 + mi * 16 + lk * 4 + r;
        int grow = m0 + row;
        float bx = sBv[row * 97 + lc0];
        float by = sBv[row * 97 + lc0 + 1];
        float bz = sBv[row * 97 + lc0 + 2];
        const float* hp = hprev + (long)grow * D_MODEL + (n0 + lc0);
        float vx = hp[0], vy = hp[1], vz = hp[2];
        float nb = sqrtf(bx * bx + by * by + bz * bz);
        nb = fmaxf(nb, EPS);
        float ha = 0.5f * nb;
        float w  = cosf(ha);
        float s  = sinf(ha) / nb;
        // faithful to reference quirk: qx from bz, qy from -by, qz from bx
        float qx = s * bz, qy = -s * by, qz = s * bx;
        float tx = 2.f * (qy * vz - qz * vy);
        float ty = 2.f * (qz * vx - qx * vz);
        float tz = 2.f * (qx * vy - qy * vx);
        float rx = vx + w * tx + (qy * tz - qz * ty);
        float ry = vy + w * ty + (qz * tx - qx * tz);
        float rz = vz + w * tz + (qx * ty - qy * tx);
        float rc = (c == 0) ? rx : ((c == 1) ? ry : rz);
        out[(long)grow * D_MODEL + gcol] =
            decay[grow] * rc + (accI[mi][ni][r] + binv);
      }
    }
}

// ---------------- fallback (r7 green kernel, hammers retained) ------------
__global__ __launch_bounds__(256, 2)
void fused_mfma3(const float* __restrict__ x,
                 const float* __restrict__ wbiv,
                 const float* __restrict__ win,
                 const float* __restrict__ hprev,
                 const float* __restrict__ wdec,
                 const float* __restrict__ bdec,
                 const float* __restrict__ bbiv,
                 const float* __restrict__ bin,
                 float* __restrict__ out) {
  __shared__ __align__(16) char smem[50688];
  __shared__ float sDecay[BM];
  unsigned short* sA  = (unsigned short*)smem;
  unsigned short* sB1 = (unsigned short*)(smem + 16384);
  unsigned short* sB2 = (unsigned short*)(smem + 28672);
  float* sBv = (float*)smem;

  const int bid = blockIdx.x;
  const int tm = bid / NTN, tn = bid % NTN;
  const int m0 = tm * BM, n0 = tn * BN;
  const int tid  = threadIdx.x;
  const int lane = tid & 63, wid = tid >> 6;
  const int wr = wid >> 1, wc = wid & 1;
  const int lr = lane & 15;
  const int lk = lane >> 4;

  {
    const float bd = bdec[0];
    const float4* wd4 = (const float4*)wdec;
    for (int rr = 0; rr < 32; ++rr) {
      int row = wid * 32 + rr;
      const float4* xr = (const float4*)(x + (long)(m0 + row) * D_MODEL);
      float acc = 0.f;
#pragma unroll
      for (int i = 0; i < 6; ++i) {
        float4 a = xr[lane + 64 * i];
        float4 b = wd4[lane + 64 * i];
        acc += a.x * b.x + a.y * b.y + a.z * b.z + a.w * b.w;
      }
      for (int off = 32; off; off >>= 1) acc += __shfl_xor(acc, off);
      if (lane == 0) sDecay[row] = 1.f / (1.f + expf(-(acc + bd)));
    }
  }

  f32x4 accB[4][3], accI[4][3];
#pragma unroll
  for (int a = 0; a < 4; ++a)
#pragma unroll
    for (int b = 0; b < 3; ++b) { accB[a][b] = (f32x4)0.f; accI[a][b] = (f32x4)0.f; }

  for (int kt = 0; kt < D_MODEL; kt += 64) {
    full_drain();
    __syncthreads();
#pragma unroll
    for (int i = 0; i < 4; ++i) {
      int f = i * 256 + tid;
      int row = f >> 3, c = f & 7;
      const float4* p = (const float4*)(x + (long)(m0 + row) * D_MODEL + kt + c * 8);
      *(ushort8*)(sA + row * 64 + c * 8) = pack8u(p[0], p[1]);
    }
#pragma unroll
    for (int i = 0; i < 6; ++i) {
      int mat = (i >= 3);
      int g = (i - 3 * mat) * 256 + tid;
      int row = g >> 3, c = g & 7;
      const float* wsrc = mat ? win : wbiv;
      const float4* p = (const float4*)(wsrc + (long)(n0 + row) * D_MODEL + kt + c * 8);
      *(ushort8*)((mat ? sB2 : sB1) + row * 64 + c * 8) = pack8u(p[0], p[1]);
    }
    full_drain();
    __syncthreads();

#pragma unroll
    for (int ks = 0; ks < 2; ++ks) {
      const int k0 = ks * 32 + lk * 8;
      bf16x8 a[4], b1[3], b2[3];
#pragma unroll
      for (int mi = 0; mi < 4; ++mi)
        a[mi] = *(const bf16x8*)(sA + (wr * 64 + mi * 16 + lr) * 64 + k0);
#pragma unroll
      for (int ni = 0; ni < 3; ++ni) {
        b1[ni] = *(const bf16x8*)(sB1 + (wc * 48 + ni * 16 + lr) * 64 + k0);
        b2[ni] = *(const bf16x8*)(sB2 + (wc * 48 + ni * 16 + lr) * 64 + k0);
      }
      full_drain();
      __builtin_amdgcn_sched_barrier(0);
#pragma unroll
      for (int mi = 0; mi < 4; ++mi)
#pragma unroll
        for (int ni = 0; ni < 3; ++ni)
          accB[mi][ni] = __builtin_amdgcn_mfma_f32_16x16x32_bf16(
              a[mi], b1[ni], accB[mi][ni], 0, 0, 0);
      __builtin_amdgcn_sched_barrier(0);
#pragma unroll
      for (int mi = 0; mi < 4; ++mi)
#pragma unroll
        for (int ni = 0; ni < 3; ++ni)
          accI[mi][ni] = __builtin_amdgcn_mfma_f32_16x16x32_bf16(
              a[mi], b2[ni], accI[mi][ni], 0, 0, 0);
      __builtin_amdgcn_sched_barrier(0);
    }
  }

  full_drain();
  __syncthreads();
#pragma unroll
  for (int mi = 0; mi < 4; ++mi)
#pragma unroll
    for (int ni = 0; ni < 3; ++ni) {
      int col = wc * 48 + ni * 16 + lr;
      float bb = bbiv[n0 + col];
#pragma unroll
      for (int r = 0; r < 4; ++r) {
        int row = wr * 64 + mi * 16 + lk * 4 + r;
        sBv[row * 97 + col] = accB[mi][ni][r] + bb;
      }
    }
  full_drain();
  __syncthreads();

#pragma unroll
  for (int mi = 0; mi < 4; ++mi)
#pragma unroll
    for (int ni = 0; ni < 3; ++ni) {
      int col  = wc * 48 + ni * 16 + lr;
      int gcol = n0 + col;
      int c    = (col % 3);
      int lc0  = col - c;
      float binv = bin[gcol];
#pragma unroll
      for (int r = 0; r < 4; ++r) {
        int row  = wr * 64 + mi * 16 + lk * 4 + r;
        int grow = m0 + row;
        float bx = sBv[row * 97 + lc0];
        float by = sBv[row * 97 + lc0 + 1];
        float bz = sBv[row * 97 + lc0 + 2];
        const float* hp = hprev + (long)grow * D_MODEL + (n0 + lc0);
        float vx = hp[0], vy = hp[1], vz = hp[2];
        float nb = sqrtf(bx * bx + by * by + bz * bz);
        nb = fmaxf(nb, EPS);
        float ha = 0.5f * nb;
        float w  = cosf(ha);
        float s  = sinf(ha) / nb;
        float qx = s * bz, qy = -s * by, qz = s * bx;
        float tx = 2.f * (qy * vz - qz * vy);
        float ty = 2.f * (qz * vx - qx * vz);
        float tz = 2.f * (qx * vy - qy * vx);
        float rx = vx + w * tx + (qy * tz - qz * ty);
        float ry = vy + w * ty + (qz * tx - qx * tz);
        float rz = vz + w * tz + (qx * ty - qy * tx);
        float rc = (c == 0) ? rx : ((c == 1) ? ry : rz);
        out[(long)grow * D_MODEL + gcol] =
            sDecay[row] * rc + (accI[mi][ni][r] + binv);
      }
    }
}

// -------------------------------------------------------------------------
extern "C" void kernel_launch(void* const* d_in, const int* in_sizes, int n_in,
                              void* d_out, int out_size, void* d_ws, size_t ws_size,
                              hipStream_t stream) {
  const float* x     = (const float*)d_in[0];
  const float* hprev = (const float*)d_in[1];
  const float* wbiv  = (const float*)d_in[2];
  const float* bbiv  = (const float*)d_in[3];
  const float* wdec  = (const float*)d_in[4];
  const float* bdec  = (const float*)d_in[5];
  const float* win   = (const float*)d_in[6];
  const float* bin   = (const float*)d_in[7];
  float* out = (float*)d_out;

  const size_t XB_B  = 25165824;   // 8192*1536*2
  const size_t WB_B  = 9437184;    // 2*1536*1536*2
  const size_t DC_B  = 32768;      // 8192*4

  if (ws_size >= XB_B + WB_B + DC_B) {
    char* ws = (char*)d_ws;
    unsigned short* xb = (unsigned short*)ws;
    unsigned short* wb = (unsigned short*)(ws + XB_B);
    float* decay       = (float*)(ws + XB_B + WB_B);
    prep_all<<<dim3(3072), dim3(256), 0, stream>>>(
        x, wdec, bdec, wbiv, win, xb, wb, decay);
    fused_main<<<dim3(NTM * NTN), dim3(512), 0, stream>>>(
        xb, wb, hprev, decay, bbiv, bin, out);
  } else {
    fused_mfma3<<<dim3(NTM * NTN), dim3(256), 0, stream>>>(
        x, wbiv, win, hprev, wdec, bdec, bbiv, bin, out);
  }
}

// Round 18
// 124.822 us; speedup vs baseline: 1.0792x; 1.0792x over previous
//
#include <hip/hip_runtime.h>
#include <cstdint>

#define D_MODEL 1536
#define BATCH   8192
#define EPS     1e-8f

#define BM 128
#define BN 96        // multiple of 3: quaternion blocks never straddle a tile
#define BK 64
#define NT (D_MODEL / BK)    // 24 K-tiles
#define NTN (D_MODEL / BN)   // 16
#define NTM (BATCH / BM)     // 64
#define BUF 40960            // bytes per LDS buffer (A 16384 + B1 12288 + B2 12288)

typedef __attribute__((ext_vector_type(8))) short bf16x8;
typedef __attribute__((ext_vector_type(8))) unsigned short ushort8;
typedef __attribute__((ext_vector_type(4))) float f32x4;

__device__ __forceinline__ unsigned short f2bf(float f) {
  unsigned u = __builtin_bit_cast(unsigned, f);
  u += 0x7fffu + ((u >> 16) & 1u);            // round-to-nearest-even
  return (unsigned short)(u >> 16);
}

__device__ __forceinline__ ushort8 pack8u(float4 a, float4 b) {
  ushort8 o;
  o[0] = f2bf(a.x); o[1] = f2bf(a.y); o[2] = f2bf(a.z); o[3] = f2bf(a.w);
  o[4] = f2bf(b.x); o[5] = f2bf(b.y); o[6] = f2bf(b.z); o[7] = f2bf(b.w);
  return o;
}

__device__ __forceinline__ void full_drain() {
  asm volatile("s_waitcnt vmcnt(0) lgkmcnt(0)" ::: "memory");
}
__device__ __forceinline__ void vm_drain() {
  asm volatile("s_waitcnt vmcnt(0)" ::: "memory");
}
__device__ __forceinline__ void lgkm_drain() {
  asm volatile("s_waitcnt lgkmcnt(0)" ::: "memory");
}

__device__ __forceinline__ void load_lds16(const void* g, void* l) {
  __builtin_amdgcn_global_load_lds(
      (const __attribute__((address_space(1))) unsigned int*)g,
      (__attribute__((address_space(3))) unsigned int*)l,
      16, 0, 0);
}

// ---------------- prep_all: x->bf16 + decay (blocks 0..2047),
//                  weights->bf16 (blocks 2048..3071) ----------------------
__global__ void prep_all(const float* __restrict__ x,
                         const float* __restrict__ wdec,
                         const float* __restrict__ bdec,
                         const float* __restrict__ wbiv,
                         const float* __restrict__ win,
                         unsigned short* __restrict__ xb,
                         unsigned short* __restrict__ wb,
                         float* __restrict__ decay) {
  const int b = blockIdx.x;
  if (b < 2048) {
    int row  = (int)((b * 256 + threadIdx.x) >> 6);
    int lane = threadIdx.x & 63;
    const float4* xr = (const float4*)(x + (long)row * D_MODEL);
    const float4* wr = (const float4*)wdec;
    unsigned short* xo = xb + (long)row * D_MODEL;
    float acc = 0.f;
#pragma unroll
    for (int i = 0; i < 6; ++i) {                // 6*64*4 = 1536
      float4 a = xr[lane + 64 * i];
      float4 w = wr[lane + 64 * i];
      acc += a.x * w.x + a.y * w.y + a.z * w.z + a.w * w.w;
      ushort4 o;
      o.x = f2bf(a.x); o.y = f2bf(a.y); o.z = f2bf(a.z); o.w = f2bf(a.w);
      *(ushort4*)(xo + (lane + 64 * i) * 4) = o;
    }
    for (int off = 32; off; off >>= 1) acc += __shfl_xor(acc, off);
    if (lane == 0) decay[row] = 1.f / (1.f + expf(-(acc + bdec[0])));
  } else {
    const long NW4 = (long)D_MODEL * D_MODEL / 4;
    for (long i = (long)(b - 2048) * 256 + threadIdx.x; i < 2 * NW4;
         i += (long)1024 * 256) {
      const float4* src = (i < NW4) ? (const float4*)wbiv : (const float4*)win;
      long j = (i < NW4) ? i : (i - NW4);
      float4 v = src[j];
      ushort4 o;
      o.x = f2bf(v.x); o.y = f2bf(v.y); o.z = f2bf(v.z); o.w = f2bf(v.w);
      *(ushort4*)(wb + 4 * i) = o;
    }
  }
}

// ---------------- main: dual-GEMM + quaternion epilogue -------------------
// Green r16 body verbatim + T1 XCD-bijective blockIdx swizzle
// (nwg=1024, 1024%8==0 -> swz = (raw%8)*128 + raw/8).
__global__ __launch_bounds__(512, 2)
void fused_main(const unsigned short* __restrict__ xb,
                const unsigned short* __restrict__ wb,
                const float* __restrict__ hprev,
                const float* __restrict__ decay,
                const float* __restrict__ bbiv,
                const float* __restrict__ bin,
                float* __restrict__ out) {
  __shared__ __align__(16) char smem[2 * BUF];   // 81920 B -> 2 blocks/CU
  float* sBv = (float*)smem;                     // [128][97] epilogue overlay

  const int raw = blockIdx.x;
  const int bid = (raw & 7) * 128 + (raw >> 3);  // XCD-contiguous logical id
  const int tm = bid / NTN, tn = bid % NTN;
  const int m0 = tm * BM, n0 = tn * BN;
  const int tid  = threadIdx.x;
  const int lane = tid & 63, wid = tid >> 6;
  const int wr = wid >> 1, wc = wid & 1;   // 4x2 wave grid: 32x48 per wave
  const int lr = lane & 15;                // fragment row/col
  const int lk = lane >> 4;                // k-octet group

  // ---- hoisted STAGE addressing (global ptrs advance BK per tile) ----
  const unsigned short *gA0, *gA1, *gB1a, *gB1b, *gB2a, *gB2b;
  int dA0, dA1, dB1a, dB1b, dB2a, dB2b;
  {
    int f, row, c, cs;
    f = tid;        row = f >> 3; c = f & 7; cs = c ^ (row & 7);
    gA0 = xb + (long)(m0 + row) * D_MODEL + cs * 8;
    f = 512 + tid;  row = f >> 3; c = f & 7; cs = c ^ (row & 7);
    gA1 = xb + (long)(m0 + row) * D_MODEL + cs * 8;
    f = tid;        row = f >> 3; c = f & 7; cs = c ^ (row & 7);
    gB1a = wb + (long)(n0 + row) * D_MODEL + cs * 8;
    gB2a = gB1a + (long)D_MODEL * D_MODEL;
    f = 512 + tid;  row = f >> 3; c = f & 7; cs = c ^ (row & 7);
    gB1b = wb + (long)(n0 + row) * D_MODEL + cs * 8;   // used only if tid<256
    gB2b = gB1b + (long)D_MODEL * D_MODEL;
    dA0  = (wid * 64) << 4;
    dA1  = (512 + wid * 64) << 4;
    dB1a = 16384 + ((wid * 64) << 4);
    dB1b = 16384 + ((512 + wid * 64) << 4);
    dB2a = dB1a + 12288;
    dB2b = dB1b + 12288;
  }

  auto STAGE = [&](int bb) {
    load_lds16(gA0,  smem + bb + dA0);
    load_lds16(gA1,  smem + bb + dA1);
    load_lds16(gB1a, smem + bb + dB1a);
    if (tid < 256) load_lds16(gB1b, smem + bb + dB1b);
    load_lds16(gB2a, smem + bb + dB2a);
    if (tid < 256) load_lds16(gB2b, smem + bb + dB2b);
    gA0 += BK; gA1 += BK; gB1a += BK; gB1b += BK; gB2a += BK; gB2b += BK;
  };

  // acc*[mi][ni][r] == C[wr*32+mi*16+lk*4+r][n0+wc*48+ni*16+lr]
  f32x4 accB[2][3], accI[2][3];
#pragma unroll
  for (int a = 0; a < 2; ++a)
#pragma unroll
    for (int b = 0; b < 3; ++b) { accB[a][b] = (f32x4)0.f; accI[a][b] = (f32x4)0.f; }

  // prologue: fill buffer 0
  STAGE(0);
  vm_drain();
  __syncthreads();

  for (int t = 0; t < NT; ++t) {
    const int cur = (t & 1) * BUF;
    if (t + 1 < NT) STAGE(((t + 1) & 1) * BUF);   // prefetch next tile

    const unsigned short* cA  = (const unsigned short*)(smem + cur);
    const unsigned short* cB1 = (const unsigned short*)(smem + cur + 16384);
    const unsigned short* cB2 = (const unsigned short*)(smem + cur + 28672);

#pragma unroll
    for (int ks = 0; ks < 2; ++ks) {
      const int slot = ks * 4 + lk;        // logical k-octet slot (0..7)
      bf16x8 a[2], b1[3], b2[3];
#pragma unroll
      for (int mi = 0; mi < 2; ++mi) {
        int R = wr * 32 + mi * 16 + lr;
        a[mi] = *(const bf16x8*)(cA + R * 64 + (slot ^ (R & 7)) * 8);
      }
#pragma unroll
      for (int ni = 0; ni < 3; ++ni) {
        int R = wc * 48 + ni * 16 + lr;
        b1[ni] = *(const bf16x8*)(cB1 + R * 64 + (slot ^ (R & 7)) * 8);
        b2[ni] = *(const bf16x8*)(cB2 + R * 64 + (slot ^ (R & 7)) * 8);
      }
      lgkm_drain();                          // operands in registers
      __builtin_amdgcn_sched_barrier(0);     // no reorder into MFMA chain
#pragma unroll
      for (int mi = 0; mi < 2; ++mi)
#pragma unroll
        for (int ni = 0; ni < 3; ++ni)
          accB[mi][ni] = __builtin_amdgcn_mfma_f32_16x16x32_bf16(
              a[mi], b1[ni], accB[mi][ni], 0, 0, 0);
      __builtin_amdgcn_sched_barrier(0);     // no chain interleave
#pragma unroll
      for (int mi = 0; mi < 2; ++mi)
#pragma unroll
        for (int ni = 0; ni < 3; ++ni)
          accI[mi][ni] = __builtin_amdgcn_mfma_f32_16x16x32_bf16(
              a[mi], b2[ni], accI[mi][ni], 0, 0, 0);
      __builtin_amdgcn_sched_barrier(0);
    }

    vm_drain();        // prefetched tile landed; LDS reads already drained
    __syncthreads();   // safe to overwrite buffer (t&1) next iteration
  }

  // ---- epilogue (r16 logic) ----
#pragma unroll
  for (int mi = 0; mi < 2; ++mi)
#pragma unroll
    for (int ni = 0; ni < 3; ++ni) {
      int col = wc * 48 + ni * 16 + lr;
      float bb = bbiv[n0 + col];
#pragma unroll
      for (int r = 0; r < 4; ++r) {
        int row = wr * 32 + mi * 16 + lk * 4 + r;
        sBv[row * 97 + col] = accB[mi][ni][r] + bb;
      }
    }
  full_drain();
  __syncthreads();

#pragma unroll
  for (int mi = 0; mi < 2; ++mi)
#pragma unroll
    for (int ni = 0; ni < 3; ++ni) {
      int col  = wc * 48 + ni * 16 + lr;
      int gcol = n0 + col;
      int c    = (col % 3);        // n0 % 3 == 0
      int lc0  = col - c;
      float binv = bin[gcol];
#pragma unroll
      for (int r = 0; r < 4; ++r) {
        int row  = wr * 32 + mi * 16 + lk * 4 + r;
        int grow = m0 + row;
        float bx = sBv[row * 97 + lc0];
        float by = sBv[row * 97 + lc0 + 1];
        float bz = sBv[row * 97 + lc0 + 2];
        const float* hp = hprev + (long)grow * D_MODEL + (n0 + lc0);
        float vx = hp[0], vy = hp[1], vz = hp[2];
        float nb = sqrtf(bx * bx + by * by + bz * bz);
        nb = fmaxf(nb, EPS);
        float ha = 0.5f * nb;
        float w  = cosf(ha);
        float s  = sinf(ha) / nb;
        // faithful to reference quirk: qx from bz, qy from -by, qz from bx
        float qx = s * bz, qy = -s * by, qz = s * bx;
        float tx = 2.f * (qy * vz - qz * vy);
        float ty = 2.f * (qz * vx - qx * vz);
        float tz = 2.f * (qx * vy - qy * vx);
        float rx = vx + w * tx + (qy * tz - qz * ty);
        float ry = vy + w * ty + (qz * tx - qx * tz);
        float rz = vz + w * tz + (qx * ty - qy * tx);
        float rc = (c == 0) ? rx : ((c == 1) ? ry : rz);
        out[(long)grow * D_MODEL + gcol] =
            decay[grow] * rc + (accI[mi][ni][r] + binv);
      }
    }
}

// ---------------- fallback (r7 green kernel, hammers retained) ------------
__global__ __launch_bounds__(256, 2)
void fused_mfma3(const float* __restrict__ x,
                 const float* __restrict__ wbiv,
                 const float* __restrict__ win,
                 const float* __restrict__ hprev,
                 const float* __restrict__ wdec,
                 const float* __restrict__ bdec,
                 const float* __restrict__ bbiv,
                 const float* __restrict__ bin,
                 float* __restrict__ out) {
  __shared__ __align__(16) char smem[50688];
  __shared__ float sDecay[BM];
  unsigned short* sA  = (unsigned short*)smem;
  unsigned short* sB1 = (unsigned short*)(smem + 16384);
  unsigned short* sB2 = (unsigned short*)(smem + 28672);
  float* sBv = (float*)smem;

  const int bid = blockIdx.x;
  const int tm = bid / NTN, tn = bid % NTN;
  const int m0 = tm * BM, n0 = tn * BN;
  const int tid  = threadIdx.x;
  const int lane = tid & 63, wid = tid >> 6;
  const int wr = wid >> 1, wc = wid & 1;
  const int lr = lane & 15;
  const int lk = lane >> 4;

  {
    const float bd = bdec[0];
    const float4* wd4 = (const float4*)wdec;
    for (int rr = 0; rr < 32; ++rr) {
      int row = wid * 32 + rr;
      const float4* xr = (const float4*)(x + (long)(m0 + row) * D_MODEL);
      float acc = 0.f;
#pragma unroll
      for (int i = 0; i < 6; ++i) {
        float4 a = xr[lane + 64 * i];
        float4 b = wd4[lane + 64 * i];
        acc += a.x * b.x + a.y * b.y + a.z * b.z + a.w * b.w;
      }
      for (int off = 32; off; off >>= 1) acc += __shfl_xor(acc, off);
      if (lane == 0) sDecay[row] = 1.f / (1.f + expf(-(acc + bd)));
    }
  }

  f32x4 accB[4][3], accI[4][3];
#pragma unroll
  for (int a = 0; a < 4; ++a)
#pragma unroll
    for (int b = 0; b < 3; ++b) { accB[a][b] = (f32x4)0.f; accI[a][b] = (f32x4)0.f; }

  for (int kt = 0; kt < D_MODEL; kt += 64) {
    full_drain();
    __syncthreads();
#pragma unroll
    for (int i = 0; i < 4; ++i) {
      int f = i * 256 + tid;
      int row = f >> 3, c = f & 7;
      const float4* p = (const float4*)(x + (long)(m0 + row) * D_MODEL + kt + c * 8);
      *(ushort8*)(sA + row * 64 + c * 8) = pack8u(p[0], p[1]);
    }
#pragma unroll
    for (int i = 0; i < 6; ++i) {
      int mat = (i >= 3);
      int g = (i - 3 * mat) * 256 + tid;
      int row = g >> 3, c = g & 7;
      const float* wsrc = mat ? win : wbiv;
      const float4* p = (const float4*)(wsrc + (long)(n0 + row) * D_MODEL + kt + c * 8);
      *(ushort8*)((mat ? sB2 : sB1) + row * 64 + c * 8) = pack8u(p[0], p[1]);
    }
    full_drain();
    __syncthreads();

#pragma unroll
    for (int ks = 0; ks < 2; ++ks) {
      const int k0 = ks * 32 + lk * 8;
      bf16x8 a[4], b1[3], b2[3];
#pragma unroll
      for (int mi = 0; mi < 4; ++mi)
        a[mi] = *(const bf16x8*)(sA + (wr * 64 + mi * 16 + lr) * 64 + k0);
#pragma unroll
      for (int ni = 0; ni < 3; ++ni) {
        b1[ni] = *(const bf16x8*)(sB1 + (wc * 48 + ni * 16 + lr) * 64 + k0);
        b2[ni] = *(const bf16x8*)(sB2 + (wc * 48 + ni * 16 + lr) * 64 + k0);
      }
      full_drain();
      __builtin_amdgcn_sched_barrier(0);
#pragma unroll
      for (int mi = 0; mi < 4; ++mi)
#pragma unroll
        for (int ni = 0; ni < 3; ++ni)
          accB[mi][ni] = __builtin_amdgcn_mfma_f32_16x16x32_bf16(
              a[mi], b1[ni], accB[mi][ni], 0, 0, 0);
      __builtin_amdgcn_sched_barrier(0);
#pragma unroll
      for (int mi = 0; mi < 4; ++mi)
#pragma unroll
        for (int ni = 0; ni < 3; ++ni)
          accI[mi][ni] = __builtin_amdgcn_mfma_f32_16x16x32_bf16(
              a[mi], b2[ni], accI[mi][ni], 0, 0, 0);
      __builtin_amdgcn_sched_barrier(0);
    }
  }

  full_drain();
  __syncthreads();
#pragma unroll
  for (int mi = 0; mi < 4; ++mi)
#pragma unroll
    for (int ni = 0; ni < 3; ++ni) {
      int col = wc * 48 + ni * 16 + lr;
      float bb = bbiv[n0 + col];
#pragma unroll
      for (int r = 0; r < 4; ++r) {
        int row = wr * 64 + mi * 16 + lk * 4 + r;
        sBv[row * 97 + col] = accB[mi][ni][r] + bb;
      }
    }
  full_drain();
  __syncthreads();

#pragma unroll
  for (int mi = 0; mi < 4; ++mi)
#pragma unroll
    for (int ni = 0; ni < 3; ++ni) {
      int col  = wc * 48 + ni * 16 + lr;
      int gcol = n0 + col;
      int c    = (col % 3);
      int lc0  = col - c;
      float binv = bin[gcol];
#pragma unroll
      for (int r = 0; r < 4; ++r) {
        int row  = wr * 64 + mi * 16 + lk * 4 + r;
        int grow = m0 + row;
        float bx = sBv[row * 97 + lc0];
        float by = sBv[row * 97 + lc0 + 1];
        float bz = sBv[row * 97 + lc0 + 2];
        const float* hp = hprev + (long)grow * D_MODEL + (n0 + lc0);
        float vx = hp[0], vy = hp[1], vz = hp[2];
        float nb = sqrtf(bx * bx + by * by + bz * bz);
        nb = fmaxf(nb, EPS);
        float ha = 0.5f * nb;
        float w  = cosf(ha);
        float s  = sinf(ha) / nb;
        float qx = s * bz, qy = -s * by, qz = s * bx;
        float tx = 2.f * (qy * vz - qz * vy);
        float ty = 2.f * (qz * vx - qx * vz);
        float tz = 2.f * (qx * vy - qy * vx);
        float rx = vx + w * tx + (qy * tz - qz * ty);
        float ry = vy + w * ty + (qz * tx - qx * tz);
        float rz = vz + w * tz + (qx * ty - qy * tx);
        float rc = (c == 0) ? rx : ((c == 1) ? ry : rz);
        out[(long)grow * D_MODEL + gcol] =
            sDecay[row] * rc + (accI[mi][ni][r] + binv);
      }
    }
}

// -------------------------------------------------------------------------
extern "C" void kernel_launch(void* const* d_in, const int* in_sizes, int n_in,
                              void* d_out, int out_size, void* d_ws, size_t ws_size,
                              hipStream_t stream) {
  const float* x     = (const float*)d_in[0];
  const float* hprev = (const float*)d_in[1];
  const float* wbiv  = (const float*)d_in[2];
  const float* bbiv  = (const float*)d_in[3];
  const float* wdec  = (const float*)d_in[4];
  const float* bdec  = (const float*)d_in[5];
  const float* win   = (const float*)d_in[6];
  const float* bin   = (const float*)d_in[7];
  float* out = (float*)d_out;

  const size_t XB_B  = 25165824;   // 8192*1536*2
  const size_t WB_B  = 9437184;    // 2*1536*1536*2
  const size_t DC_B  = 32768;      // 8192*4

  if (ws_size >= XB_B + WB_B + DC_B) {
    char* ws = (char*)d_ws;
    unsigned short* xb = (unsigned short*)ws;
    unsigned short* wb = (unsigned short*)(ws + XB_B);
    float* decay       = (float*)(ws + XB_B + WB_B);
    prep_all<<<dim3(3072), dim3(256), 0, stream>>>(
        x, wdec, bdec, wbiv, win, xb, wb, decay);
    fused_main<<<dim3(NTM * NTN), dim3(512), 0, stream>>>(
        xb, wb, hprev, decay, bbiv, bin, out);
  } else {
    fused_mfma3<<<dim3(NTM * NTN), dim3(256), 0, stream>>>(
        x, wbiv, win, hprev, wdec, bdec, bbiv, bin, out);
  }
}

// Round 20
// 113.481 us; speedup vs baseline: 1.1871x; 1.0999x over previous
//
#include <hip/hip_runtime.h>
#include <cstdint>

#define D_MODEL 1536
#define BATCH   8192
#define EPS     1e-8f

#define BM 128
#define BN 96        // multiple of 3: quaternion blocks never straddle a tile
#define BK 64
#define NT (D_MODEL / BK)    // 24 K-tiles
#define NTN (D_MODEL / BN)   // 16
#define NTM (BATCH / BM)     // 64
#define BUF 40960            // bytes per LDS buffer (A 16384 + B1 12288 + B2 12288)

typedef __attribute__((ext_vector_type(8))) short bf16x8;
typedef __attribute__((ext_vector_type(8))) unsigned short ushort8;
typedef __attribute__((ext_vector_type(4))) float f32x4;

__device__ __forceinline__ unsigned short f2bf(float f) {
  unsigned u = __builtin_bit_cast(unsigned, f);
  u += 0x7fffu + ((u >> 16) & 1u);            // round-to-nearest-even
  return (unsigned short)(u >> 16);
}

__device__ __forceinline__ ushort8 pack8u(float4 a, float4 b) {
  ushort8 o;
  o[0] = f2bf(a.x); o[1] = f2bf(a.y); o[2] = f2bf(a.z); o[3] = f2bf(a.w);
  o[4] = f2bf(b.x); o[5] = f2bf(b.y); o[6] = f2bf(b.z); o[7] = f2bf(b.w);
  return o;
}

__device__ __forceinline__ void full_drain() {
  asm volatile("s_waitcnt vmcnt(0) lgkmcnt(0)" ::: "memory");
}
__device__ __forceinline__ void vm_drain() {
  asm volatile("s_waitcnt vmcnt(0)" ::: "memory");
}
__device__ __forceinline__ void lgkm_drain() {
  asm volatile("s_waitcnt lgkmcnt(0)" ::: "memory");
}

__device__ __forceinline__ void load_lds16(const void* g, void* l) {
  __builtin_amdgcn_global_load_lds(
      (const __attribute__((address_space(1))) unsigned int*)g,
      (__attribute__((address_space(3))) unsigned int*)l,
      16, 0, 0);
}

// ---------------- prep_all: x->bf16 + decay (blocks 0..2047),
//                  weights->bf16 (blocks 2048..3071) ----------------------
__global__ void prep_all(const float* __restrict__ x,
                         const float* __restrict__ wdec,
                         const float* __restrict__ bdec,
                         const float* __restrict__ wbiv,
                         const float* __restrict__ win,
                         unsigned short* __restrict__ xb,
                         unsigned short* __restrict__ wb,
                         float* __restrict__ decay) {
  const int b = blockIdx.x;
  if (b < 2048) {
    int row  = (int)((b * 256 + threadIdx.x) >> 6);
    int lane = threadIdx.x & 63;
    const float4* xr = (const float4*)(x + (long)row * D_MODEL);
    const float4* wr = (const float4*)wdec;
    unsigned short* xo = xb + (long)row * D_MODEL;
    float acc = 0.f;
#pragma unroll
    for (int i = 0; i < 6; ++i) {                // 6*64*4 = 1536
      float4 a = xr[lane + 64 * i];
      float4 w = wr[lane + 64 * i];
      acc += a.x * w.x + a.y * w.y + a.z * w.z + a.w * w.w;
      ushort4 o;
      o.x = f2bf(a.x); o.y = f2bf(a.y); o.z = f2bf(a.z); o.w = f2bf(a.w);
      *(ushort4*)(xo + (lane + 64 * i) * 4) = o;
    }
    for (int off = 32; off; off >>= 1) acc += __shfl_xor(acc, off);
    if (lane == 0) decay[row] = 1.f / (1.f + expf(-(acc + bdec[0])));
  } else {
    const long NW4 = (long)D_MODEL * D_MODEL / 4;
    for (long i = (long)(b - 2048) * 256 + threadIdx.x; i < 2 * NW4;
         i += (long)1024 * 256) {
      const float4* src = (i < NW4) ? (const float4*)wbiv : (const float4*)win;
      long j = (i < NW4) ? i : (i - NW4);
      float4 v = src[j];
      ushort4 o;
      o.x = f2bf(v.x); o.y = f2bf(v.y); o.z = f2bf(v.z); o.w = f2bf(v.w);
      *(ushort4*)(wb + 4 * i) = o;
    }
  }
}

// ---------------- main: dual-GEMM + quaternion epilogue -------------------
// r16 structure; VALU cuts: uniform 5-load STAGE (2560 = 5*512 chunks,
// wave-uniform regions), hoisted LDS read BYTE offsets (A=0, B1=16384,
// B2=28672 — r19's bug was doubling these), __cosf/__sinf epilogue.
// Fence pattern per region unchanged.
__global__ __launch_bounds__(512, 2)
void fused_main(const unsigned short* __restrict__ xb,
                const unsigned short* __restrict__ wb,
                const float* __restrict__ hprev,
                const float* __restrict__ decay,
                const float* __restrict__ bbiv,
                const float* __restrict__ bin,
                float* __restrict__ out) {
  __shared__ __align__(16) char smem[2 * BUF];   // 81920 B -> 2 blocks/CU
  float* sBv = (float*)smem;                     // [128][97] epilogue overlay

  const int bid = blockIdx.x;
  const int tm = bid / NTN, tn = bid % NTN;
  const int m0 = tm * BM, n0 = tn * BN;
  const int tid  = threadIdx.x;
  const int lane = tid & 63, wid = tid >> 6;
  const int wr = wid >> 1, wc = wid & 1;   // 4x2 wave grid: 32x48 per wave
  const int lr = lane & 15;                // fragment row/col
  const int lk = lane >> 4;                // k-octet group

  // ---- uniform 5-load STAGE: chunk f = i*512+tid over [0,2560) ----
  const unsigned short* gptr[5];
  int doff[5];
#pragma unroll
  for (int i = 0; i < 5; ++i) {
    int f = i * 512 + tid;
    if (f < 1024) {
      int row = f >> 3, c = f & 7, cs = c ^ (row & 7);
      gptr[i] = xb + (long)(m0 + row) * D_MODEL + cs * 8;
      doff[i] = f << 4;
    } else if (f < 1792) {
      int g = f - 1024;
      int row = g >> 3, c = g & 7, cs = c ^ (row & 7);
      gptr[i] = wb + (long)(n0 + row) * D_MODEL + cs * 8;
      doff[i] = 16384 + (g << 4);
    } else {
      int g = f - 1792;
      int row = g >> 3, c = g & 7, cs = c ^ (row & 7);
      gptr[i] = wb + (long)D_MODEL * D_MODEL + (long)(n0 + row) * D_MODEL + cs * 8;
      doff[i] = 28672 + (g << 4);
    }
  }

  auto STAGE = [&](int bb) {
#pragma unroll
    for (int i = 0; i < 5; ++i) {
      load_lds16(gptr[i], smem + bb + doff[i]);
      gptr[i] += BK;
    }
  };

  // ---- hoisted LDS read BYTE offsets (loop-invariant) ----
  // Buffer layout (bytes): A @ 0, B1 @ 16384, B2 @ 28672.
  int offA[2][2], offB1[3][2], offB2[3][2];
#pragma unroll
  for (int ks = 0; ks < 2; ++ks) {
    const int slot = ks * 4 + lk;
#pragma unroll
    for (int mi = 0; mi < 2; ++mi) {
      int R = wr * 32 + mi * 16 + lr;
      offA[mi][ks] = (R * 64 + (slot ^ (R & 7)) * 8) * 2;
    }
#pragma unroll
    for (int ni = 0; ni < 3; ++ni) {
      int R = wc * 48 + ni * 16 + lr;
      int o = (R * 64 + (slot ^ (R & 7)) * 8) * 2;
      offB1[ni][ks] = 16384 + o;
      offB2[ni][ks] = 28672 + o;
    }
  }

  // acc*[mi][ni][r] == C[wr*32+mi*16+lk*4+r][n0+wc*48+ni*16+lr]
  f32x4 accB[2][3], accI[2][3];
#pragma unroll
  for (int a = 0; a < 2; ++a)
#pragma unroll
    for (int b = 0; b < 3; ++b) { accB[a][b] = (f32x4)0.f; accI[a][b] = (f32x4)0.f; }

  // prologue: fill buffer 0
  STAGE(0);
  vm_drain();
  __syncthreads();

  for (int t = 0; t < NT; ++t) {
    const int cur = (t & 1) * BUF;
    if (t + 1 < NT) STAGE(((t + 1) & 1) * BUF);   // prefetch next tile

#pragma unroll
    for (int ks = 0; ks < 2; ++ks) {
      bf16x8 a[2], b1[3], b2[3];
#pragma unroll
      for (int mi = 0; mi < 2; ++mi)
        a[mi] = *(const bf16x8*)(smem + cur + offA[mi][ks]);
#pragma unroll
      for (int ni = 0; ni < 3; ++ni) {
        b1[ni] = *(const bf16x8*)(smem + cur + offB1[ni][ks]);
        b2[ni] = *(const bf16x8*)(smem + cur + offB2[ni][ks]);
      }
      lgkm_drain();                          // operands in registers
      __builtin_amdgcn_sched_barrier(0);     // no reorder into MFMA chain
#pragma unroll
      for (int mi = 0; mi < 2; ++mi)
#pragma unroll
        for (int ni = 0; ni < 3; ++ni)
          accB[mi][ni] = __builtin_amdgcn_mfma_f32_16x16x32_bf16(
              a[mi], b1[ni], accB[mi][ni], 0, 0, 0);
      __builtin_amdgcn_sched_barrier(0);     // no chain interleave
#pragma unroll
      for (int mi = 0; mi < 2; ++mi)
#pragma unroll
        for (int ni = 0; ni < 3; ++ni)
          accI[mi][ni] = __builtin_amdgcn_mfma_f32_16x16x32_bf16(
              a[mi], b2[ni], accI[mi][ni], 0, 0, 0);
      __builtin_amdgcn_sched_barrier(0);
    }

    vm_drain();        // prefetched tile landed; LDS reads already drained
    __syncthreads();   // safe to overwrite buffer (t&1) next iteration
  }

  // ---- epilogue (r16 logic; fast trig) ----
#pragma unroll
  for (int mi = 0; mi < 2; ++mi)
#pragma unroll
    for (int ni = 0; ni < 3; ++ni) {
      int col = wc * 48 + ni * 16 + lr;
      float bb = bbiv[n0 + col];
#pragma unroll
      for (int r = 0; r < 4; ++r) {
        int row = wr * 32 + mi * 16 + lk * 4 + r;
        sBv[row * 97 + col] = accB[mi][ni][r] + bb;
      }
    }
  full_drain();
  __syncthreads();

#pragma unroll
  for (int mi = 0; mi < 2; ++mi)
#pragma unroll
    for (int ni = 0; ni < 3; ++ni) {
      int col  = wc * 48 + ni * 16 + lr;
      int gcol = n0 + col;
      int c    = (col % 3);        // n0 % 3 == 0
      int lc0  = col - c;
      float binv = bin[gcol];
#pragma unroll
      for (int r = 0; r < 4; ++r) {
        int row  = wr * 32 + mi * 16 + lk * 4 + r;
        int grow = m0 + row;
        float bx = sBv[row * 97 + lc0];
        float by = sBv[row * 97 + lc0 + 1];
        float bz = sBv[row * 97 + lc0 + 2];
        const float* hp = hprev + (long)grow * D_MODEL + (n0 + lc0);
        float vx = hp[0], vy = hp[1], vz = hp[2];
        float nb = sqrtf(bx * bx + by * by + bz * bz);
        nb = fmaxf(nb, EPS);
        float ha = 0.5f * nb;
        float w  = __cosf(ha);
        float s  = __sinf(ha) / nb;
        // faithful to reference quirk: qx from bz, qy from -by, qz from bx
        float qx = s * bz, qy = -s * by, qz = s * bx;
        float tx = 2.f * (qy * vz - qz * vy);
        float ty = 2.f * (qz * vx - qx * vz);
        float tz = 2.f * (qx * vy - qy * vx);
        float rx = vx + w * tx + (qy * tz - qz * ty);
        float ry = vy + w * ty + (qz * tx - qx * tz);
        float rz = vz + w * tz + (qx * ty - qy * tx);
        float rc = (c == 0) ? rx : ((c == 1) ? ry : rz);
        out[(long)grow * D_MODEL + gcol] =
            decay[grow] * rc + (accI[mi][ni][r] + binv);
      }
    }
}

// ---------------- fallback (r7 green kernel, hammers retained) ------------
__global__ __launch_bounds__(256, 2)
void fused_mfma3(const float* __restrict__ x,
                 const float* __restrict__ wbiv,
                 const float* __restrict__ win,
                 const float* __restrict__ hprev,
                 const float* __restrict__ wdec,
                 const float* __restrict__ bdec,
                 const float* __restrict__ bbiv,
                 const float* __restrict__ bin,
                 float* __restrict__ out) {
  __shared__ __align__(16) char smem[50688];
  __shared__ float sDecay[BM];
  unsigned short* sA  = (unsigned short*)smem;
  unsigned short* sB1 = (unsigned short*)(smem + 16384);
  unsigned short* sB2 = (unsigned short*)(smem + 28672);
  float* sBv = (float*)smem;

  const int bid = blockIdx.x;
  const int tm = bid / NTN, tn = bid % NTN;
  const int m0 = tm * BM, n0 = tn * BN;
  const int tid  = threadIdx.x;
  const int lane = tid & 63, wid = tid >> 6;
  const int wr = wid >> 1, wc = wid & 1;
  const int lr = lane & 15;
  const int lk = lane >> 4;

  {
    const float bd = bdec[0];
    const float4* wd4 = (const float4*)wdec;
    for (int rr = 0; rr < 32; ++rr) {
      int row = wid * 32 + rr;
      const float4* xr = (const float4*)(x + (long)(m0 + row) * D_MODEL);
      float acc = 0.f;
#pragma unroll
      for (int i = 0; i < 6; ++i) {
        float4 a = xr[lane + 64 * i];
        float4 b = wd4[lane + 64 * i];
        acc += a.x * b.x + a.y * b.y + a.z * b.z + a.w * b.w;
      }
      for (int off = 32; off; off >>= 1) acc += __shfl_xor(acc, off);
      if (lane == 0) sDecay[row] = 1.f / (1.f + expf(-(acc + bd)));
    }
  }

  f32x4 accB[4][3], accI[4][3];
#pragma unroll
  for (int a = 0; a < 4; ++a)
#pragma unroll
    for (int b = 0; b < 3; ++b) { accB[a][b] = (f32x4)0.f; accI[a][b] = (f32x4)0.f; }

  for (int kt = 0; kt < D_MODEL; kt += 64) {
    full_drain();
    __syncthreads();
#pragma unroll
    for (int i = 0; i < 4; ++i) {
      int f = i * 256 + tid;
      int row = f >> 3, c = f & 7;
      const float4* p = (const float4*)(x + (long)(m0 + row) * D_MODEL + kt + c * 8);
      *(ushort8*)(sA + row * 64 + c * 8) = pack8u(p[0], p[1]);
    }
#pragma unroll
    for (int i = 0; i < 6; ++i) {
      int mat = (i >= 3);
      int g = (i - 3 * mat) * 256 + tid;
      int row = g >> 3, c = g & 7;
      const float* wsrc = mat ? win : wbiv;
      const float4* p = (const float4*)(wsrc + (long)(n0 + row) * D_MODEL + kt + c * 8);
      *(ushort8*)((mat ? sB2 : sB1) + row * 64 + c * 8) = pack8u(p[0], p[1]);
    }
    full_drain();
    __syncthreads();

#pragma unroll
    for (int ks = 0; ks < 2; ++ks) {
      const int k0 = ks * 32 + lk * 8;
      bf16x8 a[4], b1[3], b2[3];
#pragma unroll
      for (int mi = 0; mi < 4; ++mi)
        a[mi] = *(const bf16x8*)(sA + (wr * 64 + mi * 16 + lr) * 64 + k0);
#pragma unroll
      for (int ni = 0; ni < 3; ++ni) {
        b1[ni] = *(const bf16x8*)(sB1 + (wc * 48 + ni * 16 + lr) * 64 + k0);
        b2[ni] = *(const bf16x8*)(sB2 + (wc * 48 + ni * 16 + lr) * 64 + k0);
      }
      full_drain();
      __builtin_amdgcn_sched_barrier(0);
#pragma unroll
      for (int mi = 0; mi < 4; ++mi)
#pragma unroll
        for (int ni = 0; ni < 3; ++ni)
          accB[mi][ni] = __builtin_amdgcn_mfma_f32_16x16x32_bf16(
              a[mi], b1[ni], accB[mi][ni], 0, 0, 0);
      __builtin_amdgcn_sched_barrier(0);
#pragma unroll
      for (int mi = 0; mi < 4; ++mi)
#pragma unroll
        for (int ni = 0; ni < 3; ++ni)
          accI[mi][ni] = __builtin_amdgcn_mfma_f32_16x16x32_bf16(
              a[mi], b2[ni], accI[mi][ni], 0, 0, 0);
      __builtin_amdgcn_sched_barrier(0);
    }
  }

  full_drain();
  __syncthreads();
#pragma unroll
  for (int mi = 0; mi < 4; ++mi)
#pragma unroll
    for (int ni = 0; ni < 3; ++ni) {
      int col = wc * 48 + ni * 16 + lr;
      float bb = bbiv[n0 + col];
#pragma unroll
      for (int r = 0; r < 4; ++r) {
        int row = wr * 64 + mi * 16 + lk * 4 + r;
        sBv[row * 97 + col] = accB[mi][ni][r] + bb;
      }
    }
  full_drain();
  __syncthreads();

#pragma unroll
  for (int mi = 0; mi < 4; ++mi)
#pragma unroll
    for (int ni = 0; ni < 3; ++ni) {
      int col  = wc * 48 + ni * 16 + lr;
      int gcol = n0 + col;
      int c    = (col % 3);
      int lc0  = col - c;
      float binv = bin[gcol];
#pragma unroll
      for (int r = 0; r < 4; ++r) {
        int row  = wr * 64 + mi * 16 + lk * 4 + r;
        int grow = m0 + row;
        float bx = sBv[row * 97 + lc0];
        float by = sBv[row * 97 + lc0 + 1];
        float bz = sBv[row * 97 + lc0 + 2];
        const float* hp = hprev + (long)grow * D_MODEL + (n0 + lc0);
        float vx = hp[0], vy = hp[1], vz = hp[2];
        float nb = sqrtf(bx * bx + by * by + bz * bz);
        nb = fmaxf(nb, EPS);
        float ha = 0.5f * nb;
        float w  = cosf(ha);
        float s  = sinf(ha) / nb;
        float qx = s * bz, qy = -s * by, qz = s * bx;
        float tx = 2.f * (qy * vz - qz * vy);
        float ty = 2.f * (qz * vx - qx * vz);
        float tz = 2.f * (qx * vy - qy * vx);
        float rx = vx + w * tx + (qy * tz - qz * ty);
        float ry = vy + w * ty + (qz * tx - qx * tz);
        float rz = vz + w * tz + (qx * ty - qy * tx);
        float rc = (c == 0) ? rx : ((c == 1) ? ry : rz);
        out[(long)grow * D_MODEL + gcol] =
            sDecay[row] * rc + (accI[mi][ni][r] + binv);
      }
    }
}

// -------------------------------------------------------------------------
extern "C" void kernel_launch(void* const* d_in, const int* in_sizes, int n_in,
                              void* d_out, int out_size, void* d_ws, size_t ws_size,
                              hipStream_t stream) {
  const float* x     = (const float*)d_in[0];
  const float* hprev = (const float*)d_in[1];
  const float* wbiv  = (const float*)d_in[2];
  const float* bbiv  = (const float*)d_in[3];
  const float* wdec  = (const float*)d_in[4];
  const float* bdec  = (const float*)d_in[5];
  const float* win   = (const float*)d_in[6];
  const float* bin   = (const float*)d_in[7];
  float* out = (float*)d_out;

  const size_t XB_B  = 25165824;   // 8192*1536*2
  const size_t WB_B  = 9437184;    // 2*1536*1536*2
  const size_t DC_B  = 32768;      // 8192*4

  if (ws_size >= XB_B + WB_B + DC_B) {
    char* ws = (char*)d_ws;
    unsigned short* xb = (unsigned short*)ws;
    unsigned short* wb = (unsigned short*)(ws + XB_B);
    float* decay       = (float*)(ws + XB_B + WB_B);
    prep_all<<<dim3(3072), dim3(256), 0, stream>>>(
        x, wdec, bdec, wbiv, win, xb, wb, decay);
    fused_main<<<dim3(NTM * NTN), dim3(512), 0, stream>>>(
        xb, wb, hprev, decay, bbiv, bin, out);
  } else {
    fused_mfma3<<<dim3(NTM * NTN), dim3(256), 0, stream>>>(
        x, wbiv, win, hprev, wdec, bdec, bbiv, bin, out);
  }
}

// Round 21
// 110.758 us; speedup vs baseline: 1.2163x; 1.0246x over previous
//
#include <hip/hip_runtime.h>
#include <cstdint>

#define D_MODEL 1536
#define BATCH   8192
#define EPS     1e-8f

// main-kernel tile
#define BMM 256
#define BN  96       // multiple of 3: quaternion blocks never straddle a tile
#define BK  64
#define NT  (D_MODEL / BK)     // 24 K-tiles
#define NTN (D_MODEL / BN)     // 16
#define NTMM (BATCH / BMM)     // 32
#define BUF 57344              // A 32768 + B1 12288 + B2 12288
// fallback tile
#define BM 128
#define NTM (BATCH / BM)

typedef __attribute__((ext_vector_type(8))) short bf16x8;
typedef __attribute__((ext_vector_type(8))) unsigned short ushort8;
typedef __attribute__((ext_vector_type(4))) float f32x4;

__device__ __forceinline__ unsigned short f2bf(float f) {
  unsigned u = __builtin_bit_cast(unsigned, f);
  u += 0x7fffu + ((u >> 16) & 1u);            // round-to-nearest-even
  return (unsigned short)(u >> 16);
}

__device__ __forceinline__ ushort8 pack8u(float4 a, float4 b) {
  ushort8 o;
  o[0] = f2bf(a.x); o[1] = f2bf(a.y); o[2] = f2bf(a.z); o[3] = f2bf(a.w);
  o[4] = f2bf(b.x); o[5] = f2bf(b.y); o[6] = f2bf(b.z); o[7] = f2bf(b.w);
  return o;
}

__device__ __forceinline__ void full_drain() {
  asm volatile("s_waitcnt vmcnt(0) lgkmcnt(0)" ::: "memory");
}
__device__ __forceinline__ void vm_drain() {
  asm volatile("s_waitcnt vmcnt(0)" ::: "memory");
}
__device__ __forceinline__ void lgkm_drain() {
  asm volatile("s_waitcnt lgkmcnt(0)" ::: "memory");
}

__device__ __forceinline__ void load_lds16(const void* g, void* l) {
  __builtin_amdgcn_global_load_lds(
      (const __attribute__((address_space(1))) unsigned int*)g,
      (__attribute__((address_space(3))) unsigned int*)l,
      16, 0, 0);
}

// ---------------- prep_all: x->bf16 + decay (blocks 0..2047),
//                  weights->bf16 (blocks 2048..3071) ----------------------
__global__ void prep_all(const float* __restrict__ x,
                         const float* __restrict__ wdec,
                         const float* __restrict__ bdec,
                         const float* __restrict__ wbiv,
                         const float* __restrict__ win,
                         unsigned short* __restrict__ xb,
                         unsigned short* __restrict__ wb,
                         float* __restrict__ decay) {
  const int b = blockIdx.x;
  if (b < 2048) {
    int row  = (int)((b * 256 + threadIdx.x) >> 6);
    int lane = threadIdx.x & 63;
    const float4* xr = (const float4*)(x + (long)row * D_MODEL);
    const float4* wr = (const float4*)wdec;
    unsigned short* xo = xb + (long)row * D_MODEL;
    float acc = 0.f;
#pragma unroll
    for (int i = 0; i < 6; ++i) {                // 6*64*4 = 1536
      float4 a = xr[lane + 64 * i];
      float4 w = wr[lane + 64 * i];
      acc += a.x * w.x + a.y * w.y + a.z * w.z + a.w * w.w;
      ushort4 o;
      o.x = f2bf(a.x); o.y = f2bf(a.y); o.z = f2bf(a.z); o.w = f2bf(a.w);
      *(ushort4*)(xo + (lane + 64 * i) * 4) = o;
    }
    for (int off = 32; off; off >>= 1) acc += __shfl_xor(acc, off);
    if (lane == 0) decay[row] = 1.f / (1.f + expf(-(acc + bdec[0])));
  } else {
    const long NW4 = (long)D_MODEL * D_MODEL / 4;
    for (long i = (long)(b - 2048) * 256 + threadIdx.x; i < 2 * NW4;
         i += (long)1024 * 256) {
      const float4* src = (i < NW4) ? (const float4*)wbiv : (const float4*)win;
      long j = (i < NW4) ? i : (i - NW4);
      float4 v = src[j];
      ushort4 o;
      o.x = f2bf(v.x); o.y = f2bf(v.y); o.z = f2bf(v.z); o.w = f2bf(v.w);
      *(ushort4*)(wb + 4 * i) = o;
    }
  }
}

// ---------------- main: dual-GEMM + quaternion epilogue -------------------
// r20 structure with BM 128->256 (1024 threads, 16 waves, 1 block/CU):
// halves weight-panel re-reads -> staged bytes 1006->705 MB. Per-wave
// fence-region structure byte-identical to green r20.
__global__ __launch_bounds__(1024, 1)
void fused_main(const unsigned short* __restrict__ xb,
                const unsigned short* __restrict__ wb,
                const float* __restrict__ hprev,
                const float* __restrict__ decay,
                const float* __restrict__ bbiv,
                const float* __restrict__ bin,
                float* __restrict__ out) {
  __shared__ __align__(16) char smem[114688];    // max(2*BUF, 256*97*4)
  float* sBv = (float*)smem;                     // [256][97] epilogue overlay

  const int bid = blockIdx.x;
  const int tm = bid / NTN, tn = bid % NTN;
  const int m0 = tm * BMM, n0 = tn * BN;
  const int tid  = threadIdx.x;
  const int lane = tid & 63, wid = tid >> 6;     // wid 0..15
  const int wr = wid >> 1, wc = wid & 1;         // 8x2 wave grid: 32x48/wave
  const int lr = lane & 15;                      // fragment row/col
  const int lk = lane >> 4;                      // k-octet group

  // ---- STAGE addressing: 3584 chunks = 3*1024 + 512 (wave-uniform splits)
  // A: chunks 0..2047 (dest 0..32767), B1: 0..767 (dest 32768+),
  // B2: 0..767 (dest 45056+).
  const unsigned short* gptr[4];
  int doff[4];
  {
    // i=0,1: A chunks tid and 1024+tid
#pragma unroll
    for (int i = 0; i < 2; ++i) {
      int f = i * 1024 + tid;
      int row = f >> 3, c = f & 7, cs = c ^ (row & 7);
      gptr[i] = xb + (long)(m0 + row) * D_MODEL + cs * 8;
      doff[i] = f << 4;
    }
    // i=2: tid<768 -> B1 chunk tid ; tid>=768 -> B2 chunk tid-768
    if (tid < 768) {
      int g = tid;
      int row = g >> 3, c = g & 7, cs = c ^ (row & 7);
      gptr[2] = wb + (long)(n0 + row) * D_MODEL + cs * 8;
      doff[2] = 32768 + (g << 4);
    } else {
      int g = tid - 768;
      int row = g >> 3, c = g & 7, cs = c ^ (row & 7);
      gptr[2] = wb + (long)D_MODEL * D_MODEL + (long)(n0 + row) * D_MODEL + cs * 8;
      doff[2] = 45056 + (g << 4);
    }
    // i=3: tid<512 -> B2 chunk 256+tid
    {
      int g = 256 + tid;
      int row = g >> 3, c = g & 7, cs = c ^ (row & 7);
      gptr[3] = wb + (long)D_MODEL * D_MODEL + (long)(n0 + row) * D_MODEL + cs * 8;
      doff[3] = 45056 + (g << 4);
    }
  }

  auto STAGE = [&](int bb) {
    load_lds16(gptr[0], smem + bb + doff[0]);
    load_lds16(gptr[1], smem + bb + doff[1]);
    load_lds16(gptr[2], smem + bb + doff[2]);
    if (tid < 512) load_lds16(gptr[3], smem + bb + doff[3]);
    gptr[0] += BK; gptr[1] += BK; gptr[2] += BK; gptr[3] += BK;
  };

  // ---- hoisted LDS read BYTE offsets (A @ 0, B1 @ 32768, B2 @ 45056) ----
  int offA[2][2], offB1[3][2], offB2[3][2];
#pragma unroll
  for (int ks = 0; ks < 2; ++ks) {
    const int slot = ks * 4 + lk;
#pragma unroll
    for (int mi = 0; mi < 2; ++mi) {
      int R = wr * 32 + mi * 16 + lr;            // 0..255
      offA[mi][ks] = (R * 64 + (slot ^ (R & 7)) * 8) * 2;
    }
#pragma unroll
    for (int ni = 0; ni < 3; ++ni) {
      int R = wc * 48 + ni * 16 + lr;            // 0..95
      int o = (R * 64 + (slot ^ (R & 7)) * 8) * 2;
      offB1[ni][ks] = 32768 + o;
      offB2[ni][ks] = 45056 + o;
    }
  }

  // acc*[mi][ni][r] == C[wr*32+mi*16+lk*4+r][n0+wc*48+ni*16+lr]
  f32x4 accB[2][3], accI[2][3];
#pragma unroll
  for (int a = 0; a < 2; ++a)
#pragma unroll
    for (int b = 0; b < 3; ++b) { accB[a][b] = (f32x4)0.f; accI[a][b] = (f32x4)0.f; }

  // prologue: fill buffer 0
  STAGE(0);
  vm_drain();
  __syncthreads();

  for (int t = 0; t < NT; ++t) {
    const int cur = (t & 1) * BUF;
    if (t + 1 < NT) STAGE(((t + 1) & 1) * BUF);   // prefetch next tile

#pragma unroll
    for (int ks = 0; ks < 2; ++ks) {
      bf16x8 a[2], b1[3], b2[3];
#pragma unroll
      for (int mi = 0; mi < 2; ++mi)
        a[mi] = *(const bf16x8*)(smem + cur + offA[mi][ks]);
#pragma unroll
      for (int ni = 0; ni < 3; ++ni) {
        b1[ni] = *(const bf16x8*)(smem + cur + offB1[ni][ks]);
        b2[ni] = *(const bf16x8*)(smem + cur + offB2[ni][ks]);
      }
      lgkm_drain();                          // operands in registers
      __builtin_amdgcn_sched_barrier(0);     // no reorder into MFMA chain
#pragma unroll
      for (int mi = 0; mi < 2; ++mi)
#pragma unroll
        for (int ni = 0; ni < 3; ++ni)
          accB[mi][ni] = __builtin_amdgcn_mfma_f32_16x16x32_bf16(
              a[mi], b1[ni], accB[mi][ni], 0, 0, 0);
      __builtin_amdgcn_sched_barrier(0);     // no chain interleave
#pragma unroll
      for (int mi = 0; mi < 2; ++mi)
#pragma unroll
        for (int ni = 0; ni < 3; ++ni)
          accI[mi][ni] = __builtin_amdgcn_mfma_f32_16x16x32_bf16(
              a[mi], b2[ni], accI[mi][ni], 0, 0, 0);
      __builtin_amdgcn_sched_barrier(0);
    }

    vm_drain();        // prefetched tile landed; LDS reads already drained
    __syncthreads();   // safe to overwrite buffer (t&1) next iteration
  }

  // ---- epilogue (r20 logic; rows 0..255) ----
#pragma unroll
  for (int mi = 0; mi < 2; ++mi)
#pragma unroll
    for (int ni = 0; ni < 3; ++ni) {
      int col = wc * 48 + ni * 16 + lr;
      float bb = bbiv[n0 + col];
#pragma unroll
      for (int r = 0; r < 4; ++r) {
        int row = wr * 32 + mi * 16 + lk * 4 + r;
        sBv[row * 97 + col] = accB[mi][ni][r] + bb;
      }
    }
  full_drain();
  __syncthreads();

#pragma unroll
  for (int mi = 0; mi < 2; ++mi)
#pragma unroll
    for (int ni = 0; ni < 3; ++ni) {
      int col  = wc * 48 + ni * 16 + lr;
      int gcol = n0 + col;
      int c    = (col % 3);        // n0 % 3 == 0
      int lc0  = col - c;
      float binv = bin[gcol];
#pragma unroll
      for (int r = 0; r < 4; ++r) {
        int row  = wr * 32 + mi * 16 + lk * 4 + r;
        int grow = m0 + row;
        float bx = sBv[row * 97 + lc0];
        float by = sBv[row * 97 + lc0 + 1];
        float bz = sBv[row * 97 + lc0 + 2];
        const float* hp = hprev + (long)grow * D_MODEL + (n0 + lc0);
        float vx = hp[0], vy = hp[1], vz = hp[2];
        float nb = sqrtf(bx * bx + by * by + bz * bz);
        nb = fmaxf(nb, EPS);
        float ha = 0.5f * nb;
        float w  = __cosf(ha);
        float s  = __sinf(ha) / nb;
        // faithful to reference quirk: qx from bz, qy from -by, qz from bx
        float qx = s * bz, qy = -s * by, qz = s * bx;
        float tx = 2.f * (qy * vz - qz * vy);
        float ty = 2.f * (qz * vx - qx * vz);
        float tz = 2.f * (qx * vy - qy * vx);
        float rx = vx + w * tx + (qy * tz - qz * ty);
        float ry = vy + w * ty + (qz * tx - qx * tz);
        float rz = vz + w * tz + (qx * ty - qy * tx);
        float rc = (c == 0) ? rx : ((c == 1) ? ry : rz);
        out[(long)grow * D_MODEL + gcol] =
            decay[grow] * rc + (accI[mi][ni][r] + binv);
      }
    }
}

// ---------------- fallback (r7 green kernel, hammers retained) ------------
__global__ __launch_bounds__(256, 2)
void fused_mfma3(const float* __restrict__ x,
                 const float* __restrict__ wbiv,
                 const float* __restrict__ win,
                 const float* __restrict__ hprev,
                 const float* __restrict__ wdec,
                 const float* __restrict__ bdec,
                 const float* __restrict__ bbiv,
                 const float* __restrict__ bin,
                 float* __restrict__ out) {
  __shared__ __align__(16) char smem[50688];
  __shared__ float sDecay[BM];
  unsigned short* sA  = (unsigned short*)smem;
  unsigned short* sB1 = (unsigned short*)(smem + 16384);
  unsigned short* sB2 = (unsigned short*)(smem + 28672);
  float* sBv = (float*)smem;

  const int bid = blockIdx.x;
  const int tm = bid / NTN, tn = bid % NTN;
  const int m0 = tm * BM, n0 = tn * BN;
  const int tid  = threadIdx.x;
  const int lane = tid & 63, wid = tid >> 6;
  const int wr = wid >> 1, wc = wid & 1;
  const int lr = lane & 15;
  const int lk = lane >> 4;

  {
    const float bd = bdec[0];
    const float4* wd4 = (const float4*)wdec;
    for (int rr = 0; rr < 32; ++rr) {
      int row = wid * 32 + rr;
      const float4* xr = (const float4*)(x + (long)(m0 + row) * D_MODEL);
      float acc = 0.f;
#pragma unroll
      for (int i = 0; i < 6; ++i) {
        float4 a = xr[lane + 64 * i];
        float4 b = wd4[lane + 64 * i];
        acc += a.x * b.x + a.y * b.y + a.z * b.z + a.w * b.w;
      }
      for (int off = 32; off; off >>= 1) acc += __shfl_xor(acc, off);
      if (lane == 0) sDecay[row] = 1.f / (1.f + expf(-(acc + bd)));
    }
  }

  f32x4 accB[4][3], accI[4][3];
#pragma unroll
  for (int a = 0; a < 4; ++a)
#pragma unroll
    for (int b = 0; b < 3; ++b) { accB[a][b] = (f32x4)0.f; accI[a][b] = (f32x4)0.f; }

  for (int kt = 0; kt < D_MODEL; kt += 64) {
    full_drain();
    __syncthreads();
#pragma unroll
    for (int i = 0; i < 4; ++i) {
      int f = i * 256 + tid;
      int row = f >> 3, c = f & 7;
      const float4* p = (const float4*)(x + (long)(m0 + row) * D_MODEL + kt + c * 8);
      *(ushort8*)(sA + row * 64 + c * 8) = pack8u(p[0], p[1]);
    }
#pragma unroll
    for (int i = 0; i < 6; ++i) {
      int mat = (i >= 3);
      int g = (i - 3 * mat) * 256 + tid;
      int row = g >> 3, c = g & 7;
      const float* wsrc = mat ? win : wbiv;
      const float4* p = (const float4*)(wsrc + (long)(n0 + row) * D_MODEL + kt + c * 8);
      *(ushort8*)((mat ? sB2 : sB1) + row * 64 + c * 8) = pack8u(p[0], p[1]);
    }
    full_drain();
    __syncthreads();

#pragma unroll
    for (int ks = 0; ks < 2; ++ks) {
      const int k0 = ks * 32 + lk * 8;
      bf16x8 a[4], b1[3], b2[3];
#pragma unroll
      for (int mi = 0; mi < 4; ++mi)
        a[mi] = *(const bf16x8*)(sA + (wr * 64 + mi * 16 + lr) * 64 + k0);
#pragma unroll
      for (int ni = 0; ni < 3; ++ni) {
        b1[ni] = *(const bf16x8*)(sB1 + (wc * 48 + ni * 16 + lr) * 64 + k0);
        b2[ni] = *(const bf16x8*)(sB2 + (wc * 48 + ni * 16 + lr) * 64 + k0);
      }
      full_drain();
      __builtin_amdgcn_sched_barrier(0);
#pragma unroll
      for (int mi = 0; mi < 4; ++mi)
#pragma unroll
        for (int ni = 0; ni < 3; ++ni)
          accB[mi][ni] = __builtin_amdgcn_mfma_f32_16x16x32_bf16(
              a[mi], b1[ni], accB[mi][ni], 0, 0, 0);
      __builtin_amdgcn_sched_barrier(0);
#pragma unroll
      for (int mi = 0; mi < 4; ++mi)
#pragma unroll
        for (int ni = 0; ni < 3; ++ni)
          accI[mi][ni] = __builtin_amdgcn_mfma_f32_16x16x32_bf16(
              a[mi], b2[ni], accI[mi][ni], 0, 0, 0);
      __builtin_amdgcn_sched_barrier(0);
    }
  }

  full_drain();
  __syncthreads();
#pragma unroll
  for (int mi = 0; mi < 4; ++mi)
#pragma unroll
    for (int ni = 0; ni < 3; ++ni) {
      int col = wc * 48 + ni * 16 + lr;
      float bb = bbiv[n0 + col];
#pragma unroll
      for (int r = 0; r < 4; ++r) {
        int row = wr * 64 + mi * 16 + lk * 4 + r;
        sBv[row * 97 + col] = accB[mi][ni][r] + bb;
      }
    }
  full_drain();
  __syncthreads();

#pragma unroll
  for (int mi = 0; mi < 4; ++mi)
#pragma unroll
    for (int ni = 0; ni < 3; ++ni) {
      int col  = wc * 48 + ni * 16 + lr;
      int gcol = n0 + col;
      int c    = (col % 3);
      int lc0  = col - c;
      float binv = bin[gcol];
#pragma unroll
      for (int r = 0; r < 4; ++r) {
        int row  = wr * 64 + mi * 16 + lk * 4 + r;
        int grow = m0 + row;
        float bx = sBv[row * 97 + lc0];
        float by = sBv[row * 97 + lc0 + 1];
        float bz = sBv[row * 97 + lc0 + 2];
        const float* hp = hprev + (long)grow * D_MODEL + (n0 + lc0);
        float vx = hp[0], vy = hp[1], vz = hp[2];
        float nb = sqrtf(bx * bx + by * by + bz * bz);
        nb = fmaxf(nb, EPS);
        float ha = 0.5f * nb;
        float w  = cosf(ha);
        float s  = sinf(ha) / nb;
        float qx = s * bz, qy = -s * by, qz = s * bx;
        float tx = 2.f * (qy * vz - qz * vy);
        float ty = 2.f * (qz * vx - qx * vz);
        float tz = 2.f * (qx * vy - qy * vx);
        float rx = vx + w * tx + (qy * tz - qz * ty);
        float ry = vy + w * ty + (qz * tx - qx * tz);
        float rz = vz + w * tz + (qx * ty - qy * tx);
        float rc = (c == 0) ? rx : ((c == 1) ? ry : rz);
        out[(long)grow * D_MODEL + gcol] =
            sDecay[row] * rc + (accI[mi][ni][r] + binv);
      }
    }
}

// -------------------------------------------------------------------------
extern "C" void kernel_launch(void* const* d_in, const int* in_sizes, int n_in,
                              void* d_out, int out_size, void* d_ws, size_t ws_size,
                              hipStream_t stream) {
  const float* x     = (const float*)d_in[0];
  const float* hprev = (const float*)d_in[1];
  const float* wbiv  = (const float*)d_in[2];
  const float* bbiv  = (const float*)d_in[3];
  const float* wdec  = (const float*)d_in[4];
  const float* bdec  = (const float*)d_in[5];
  const float* win   = (const float*)d_in[6];
  const float* bin   = (const float*)d_in[7];
  float* out = (float*)d_out;

  const size_t XB_B  = 25165824;   // 8192*1536*2
  const size_t WB_B  = 9437184;    // 2*1536*1536*2
  const size_t DC_B  = 32768;      // 8192*4

  if (ws_size >= XB_B + WB_B + DC_B) {
    char* ws = (char*)d_ws;
    unsigned short* xb = (unsigned short*)ws;
    unsigned short* wb = (unsigned short*)(ws + XB_B);
    float* decay       = (float*)(ws + XB_B + WB_B);
    prep_all<<<dim3(3072), dim3(256), 0, stream>>>(
        x, wdec, bdec, wbiv, win, xb, wb, decay);
    fused_main<<<dim3(NTMM * NTN), dim3(1024), 0, stream>>>(
        xb, wb, hprev, decay, bbiv, bin, out);
  } else {
    fused_mfma3<<<dim3(NTM * NTN), dim3(256), 0, stream>>>(
        x, wbiv, win, hprev, wdec, bdec, bbiv, bin, out);
  }
}